// Round 9
// baseline (52.243 us; speedup 1.0000x reference)
//
#include <hip/hip_runtime.h>
#include <math.h>

#define NEGV (-10000000000.0f)

constexpr int B  = 16;
constexpr int QL = 32;
constexpr int TN = 10;
constexpr int AL = 10;
constexpr int E  = 300;
constexpr int H  = 256;
constexpr int M  = TN * AL;     // 100
constexpr int NQ = B * QL;      // 512 q slots
constexpr int NA = B * M;       // 1600 alia slots
constexpr int SQS = 304;        // padded row stride for stored aemb rows

// workspace layout (in floats)
constexpr size_t OFF_AEMB = 0;                                 // NA*SQS
constexpr size_t OFF_ATT  = OFF_AEMB + (size_t)NA * SQS;       // NA*QL
constexpr size_t OFF_P    = OFF_ATT + (size_t)NA * QL;         // NA*QL
constexpr size_t OFF_QW   = OFF_P + (size_t)NA * QL;           // NQ*H
constexpr size_t OFF_PS   = OFF_QW + (size_t)NQ * H;           // 640
// R6 lesson: in-graph 64B hipMemsetAsync cost ~19 us/iter. R7 lesson:
// device-scope threadfence+atomicAdd in 640 blocks cost ~11-14 us (fence ==
// L2 writeback on non-coherent XCDs). Keep 3 plain launches.

// ---------------------------------------------------------------------------
// K2 fused (448 blocks, 256 thr). Gathers + normalizes emb rows itself.
//  role A (blk < 320): per (b,tn,mh): atten (5 m-rows) + softmax -> ATT, P;
//    3-phase schedule: stage(raw, sa3=raw*w3) | dot(raw)||norm | finalize.
//    Scales factor out: att = aw1 + qw2 + acc_raw*scA*scQ + bias.
//  role B (blk >= 320): QW = Qemb_n @ enc_w[:300] (64 rowgroups x 2 halves).
// ---------------------------------------------------------------------------
__global__ __launch_bounds__(256) void k2_fused(
    const int* __restrict__ q, const int* __restrict__ alia,
    const float* __restrict__ emb,
    const float* __restrict__ sim_w, const float* __restrict__ sim_b,
    const float* __restrict__ enc_w, float* __restrict__ ws) {
  __shared__ float smem[12992];      // 52 KB -> 3 blocks/CU
  int tid = threadIdx.x;
  int wid = tid >> 6, lane = tid & 63;

  if (blockIdx.x < 320) {
    // ================= role A =================
    int mh = blockIdx.x & 1, btn = blockIdx.x >> 1;
    int b = btn / TN;
    int bm0 = btn * AL + mh * 5;
    float* sq    = smem;                        // [32][308] raw q rows
    float* sa    = smem + 32 * 308;             // [5][304] raw a rows
    float* sa3   = sa + 5 * 304;                // [5][304] raw a * w3
    float* s_qw2 = sa3 + 5 * 304;               // [32] (W2.q_raw)*scQ
    float* s_scQ = s_qw2 + 32;                  // [32]
    float* s_aw1 = s_scQ + 32;                  // [8] (W1.a_raw)*scA
    float* s_scA = s_aw1 + 8;                   // [8]

    const float* w3 = sim_w + 2 * E;
    // phase 0: stage raw rows; fold w3 into sa3 at load time
    for (int i = tid; i < 32 * 75; i += 256) {
      int r = i / 75, e4 = i % 75;
      int idx = q[b * QL + r];
      *(float4*)&sq[r * 308 + e4 * 4] =
          *(const float4*)&emb[(size_t)idx * E + e4 * 4];
    }
    for (int i = tid; i < 5 * 75; i += 256) {
      int j = i / 75, e4 = i % 75;
      int idx = alia[bm0 + j];
      float4 v = *(const float4*)&emb[(size_t)idx * E + e4 * 4];
      float4 wv = *(const float4*)&w3[e4 * 4];
      *(float4*)&sa[j * 304 + e4 * 4] = v;
      float4 t; t.x = v.x*wv.x; t.y = v.y*wv.y; t.z = v.z*wv.z; t.w = v.w*wv.w;
      *(float4*)&sa3[j * 304 + e4 * 4] = t;
    }
    __syncthreads();

    // phase 1: waves 0-2 raw dot; wave 3 norms all 37 rows concurrently
    int g = lane & 31, l = lane >> 5;
    int m = wid * 2 + l;                 // 0..5 (5 unused)
    float acc = 0.f;
    if (wid < 3) {
      const float* qr = &sq[g * 308];
      const float* ar = &sa3[(m % 5) * 304];
      for (int e4 = 0; e4 < 75; ++e4) {
        float4 qv = *(const float4*)&qr[e4 * 4];
        float4 av = *(const float4*)&ar[e4 * 4];
        acc += av.x*qv.x + av.y*qv.y + av.z*qv.z + av.w*qv.w;
      }
    } else {
      for (int r = 0; r < 37; ++r) {
        bool isa = r >= 32;
        const float* row = isa ? &sa[(r - 32) * 304] : &sq[r * 308];
        const float* W = isa ? sim_w : (sim_w + E);
        float ss = 0.f, dw = 0.f;
        for (int e = lane; e < E; e += 64) {
          float v = row[e];
          ss += v * v;
          dw += v * W[e];
        }
        #pragma unroll
        for (int off = 32; off > 0; off >>= 1) {
          ss += __shfl_xor(ss, off);
          dw += __shfl_xor(dw, off);
        }
        if (lane == 0) {
          int idx = isa ? alia[bm0 + (r - 32)] : q[b * QL + r];
          float scale = (idx == 0) ? 0.f : (1.f / fmaxf(sqrtf(ss), 1e-12f));
          if (isa) { s_scA[r - 32] = scale; s_aw1[r - 32] = dw * scale; }
          else     { s_scQ[r] = scale;      s_qw2[r] = dw * scale; }
        }
      }
    }
    __syncthreads();

    // phase 2: write normalized aemb rows; finalize att + softmax
    for (int i = tid; i < 5 * 75; i += 256) {
      int j = i / 75, e4 = i % 75;
      float sc = s_scA[j];
      float4 v = *(const float4*)&sa[j * 304 + e4 * 4];
      float4 vn; vn.x = v.x*sc; vn.y = v.y*sc; vn.z = v.z*sc; vn.w = v.w*sc;
      *(float4*)&ws[OFF_AEMB + (size_t)(bm0 + j) * SQS + e4 * 4] = vn;
    }
    if (wid < 3 && m < 5) {
      int bm = bm0 + m;
      float att = s_aw1[m] + s_qw2[g] + acc * s_scA[m] * s_scQ[g] + sim_b[0];
      if (!(alia[bm] != 0 && q[b * QL + g] != 0)) att = NEGV;
      ws[OFF_ATT + (size_t)bm * QL + g] = att;
      float mx = att;
      #pragma unroll
      for (int off = 1; off < 32; off <<= 1) mx = fmaxf(mx, __shfl_xor(mx, off));
      float ex = expf(att - mx);
      float sm = ex;
      #pragma unroll
      for (int off = 1; off < 32; off <<= 1) sm += __shfl_xor(sm, off);
      ws[OFF_P + (size_t)bm * QL + g] = ex / sm;
    }
  } else {
    // ================= role B: QW GEMM (512 x 300 @ 300 x 256) ============
    int rg = blockIdx.x - 320;
    int nh = rg & 1, rgi = rg >> 1;     // 64 rowgroups of 8 q-slots
    int slot0 = rgi * 8;
    float* sQ = smem;                   // [8][304] raw q rows
    float* spart = smem + 8 * 304;      // [kq2][j][c][4] = 4096
    float* s_scB = spart + 4096;        // [8]

    for (int i = tid; i < 8 * 75; i += 256) {
      int r = i / 75, e4 = i % 75;
      int idx = q[slot0 + r];
      *(float4*)&sQ[r * 304 + e4 * 4] =
          *(const float4*)&emb[(size_t)idx * E + e4 * 4];
    }
    __syncthreads();
    for (int r = wid; r < 8; r += 4) {
      const float* row = &sQ[r * 304];
      float ss = 0.f;
      for (int e = lane; e < E; e += 64) { float v = row[e]; ss += v * v; }
      #pragma unroll
      for (int off = 32; off > 0; off >>= 1) ss += __shfl_xor(ss, off);
      if (lane == 0) {
        int idx = q[slot0 + r];
        s_scB[r] = (idx == 0) ? 0.f : (1.f / fmaxf(sqrtf(ss), 1e-12f));
      }
    }
    __syncthreads();

    int c = tid & 31, kq = tid >> 5;    // thread handles cols c*4..c*4+3
    int ks = kq * 40;
    int nch = (kq == 7) ? 5 : 10;       // 7*40 + 20 = 300
    float acc[8][4] = {};
    for (int ch = 0; ch < nch; ++ch) {
      int k = ks + ch * 4;
      float4 a[8];
      #pragma unroll
      for (int j = 0; j < 8; j++) a[j] = *(const float4*)&sQ[j * 304 + k];
      const float* wp = enc_w + (size_t)k * H + nh * 128 + c * 4;
      #pragma unroll
      for (int e = 0; e < 4; e++) {
        float4 wv = *(const float4*)&wp[e * H];
        #pragma unroll
        for (int j = 0; j < 8; j++) {
          float av = (e == 0) ? a[j].x : (e == 1) ? a[j].y
                   : (e == 2) ? a[j].z : a[j].w;
          acc[j][0] += av * wv.x; acc[j][1] += av * wv.y;
          acc[j][2] += av * wv.z; acc[j][3] += av * wv.w;
        }
      }
    }
    // kq-pair pre-reduce across the wave halves (kq, kq^1)
    #pragma unroll
    for (int j = 0; j < 8; j++)
      #pragma unroll
      for (int nc = 0; nc < 4; nc++) acc[j][nc] += __shfl_xor(acc[j][nc], 32);
    if ((kq & 1) == 0) {
      int kq2 = kq >> 1;
      #pragma unroll
      for (int j = 0; j < 8; j++) {
        float4 t; t.x = acc[j][0]; t.y = acc[j][1]; t.z = acc[j][2]; t.w = acc[j][3];
        *(float4*)&spart[((kq2 * 8 + j) * 32 + c) * 4] = t;
      }
    }
    __syncthreads();
    #pragma unroll
    for (int t = 0; t < 4; t++) {
      int o = tid + t * 256;
      int j = o >> 7, colh = o & 127;
      float s = 0.f;
      #pragma unroll
      for (int kk = 0; kk < 4; kk++)
        s += spart[((kk * 8 + j) * 32 + (colh >> 2)) * 4 + (colh & 3)];
      ws[OFF_QW + (size_t)(slot0 + j) * H + nh * 128 + colh] = s * s_scB[j];
    }
  }
}

// ---------------------------------------------------------------------------
// K2b: enc = relu(P@QW + aemb_n@W2enc + bias), summed over 5-row half, dotted
// with qlin_w -> PS[blk]. No atomics/fences. 17 KB LDS -> 9 blocks/CU.
// grid = 640 blocks (btn, jh, nh), 256 threads = 32c x 8kq.
// ---------------------------------------------------------------------------
__global__ __launch_bounds__(256) void k2b_enc(
    const float* __restrict__ enc_w, const float* __restrict__ enc_b,
    const float* __restrict__ qlin_w, float* __restrict__ ws) {
  int blk = blockIdx.x;
  int nh = blk & 1, jh = (blk >> 1) & 1, btn = blk >> 2;
  int b = btn / TN;
  int tid = threadIdx.x;
  int c = tid & 31, kq = tid >> 5;    // thread handles cols c*4..c*4+3
  int bm0 = btn * AL + jh * 5;

  __shared__ float sA[5 * 304];
  __shared__ float sP[5 * 32];
  __shared__ float spart[4 * 5 * 32 * 4];   // kq-pair-reduced partials
  __shared__ float s_red[2];

  const float* ga = ws + OFF_AEMB + (size_t)bm0 * SQS;
  for (int i = tid; i < 5 * 75; i += 256) {
    int j = i / 75, e4 = i % 75;
    *(float4*)&sA[j * 304 + e4 * 4] = *(const float4*)&ga[j * SQS + e4 * 4];
  }
  if (tid < 160) sP[tid] = ws[OFF_P + (size_t)bm0 * QL + tid];
  __syncthreads();

  float acc[5][4] = {};

  // P @ QW part: this kq handles pk = kq*4 .. kq*4+3
  {
    float4 pv[5];
    #pragma unroll
    for (int j = 0; j < 5; j++) pv[j] = *(const float4*)&sP[j * 32 + kq * 4];
    const float* qwb = ws + OFF_QW + (size_t)(b * QL + kq * 4) * H + nh * 128 + c * 4;
    #pragma unroll
    for (int pp = 0; pp < 4; pp++) {
      float4 wv = *(const float4*)&qwb[pp * H];
      #pragma unroll
      for (int j = 0; j < 5; j++) {
        float p = (pp == 0) ? pv[j].x : (pp == 1) ? pv[j].y
                : (pp == 2) ? pv[j].z : pv[j].w;
        acc[j][0] += p * wv.x; acc[j][1] += p * wv.y;
        acc[j][2] += p * wv.z; acc[j][3] += p * wv.w;
      }
    }
  }

  // aemb_n @ W2enc part
  int ks = kq * 40;
  int nch = (kq == 7) ? 5 : 10;         // 7*40 + 20 = 300
  for (int ch = 0; ch < nch; ++ch) {
    int k = ks + ch * 4;
    float4 a[5];
    #pragma unroll
    for (int j = 0; j < 5; j++) a[j] = *(const float4*)&sA[j * 304 + k];
    const float* wp = enc_w + (size_t)(E + k) * H + nh * 128 + c * 4;
    #pragma unroll
    for (int e = 0; e < 4; e++) {
      float4 wv = *(const float4*)&wp[e * H];
      #pragma unroll
      for (int j = 0; j < 5; j++) {
        float av = (e == 0) ? a[j].x : (e == 1) ? a[j].y
                 : (e == 2) ? a[j].z : a[j].w;
        acc[j][0] += av * wv.x; acc[j][1] += av * wv.y;
        acc[j][2] += av * wv.z; acc[j][3] += av * wv.w;
      }
    }
  }

  // kq-pair pre-reduce across wave halves, then 4-deep LDS partials
  #pragma unroll
  for (int j = 0; j < 5; j++)
    #pragma unroll
    for (int nc = 0; nc < 4; nc++) acc[j][nc] += __shfl_xor(acc[j][nc], 32);
  if ((kq & 1) == 0) {
    int kq2 = kq >> 1;
    #pragma unroll
    for (int j = 0; j < 5; j++) {
      float4 t; t.x = acc[j][0]; t.y = acc[j][1]; t.z = acc[j][2]; t.w = acc[j][3];
      *(float4*)&spart[((kq2 * 5 + j) * 32 + c) * 4] = t;
    }
  }
  __syncthreads();

  float v = 0.f;
  if (tid < 128) {
    int colh = tid, col = nh * 128 + colh;
    float bias = enc_b[col];
    float s = 0.f;
    #pragma unroll
    for (int j = 0; j < 5; j++) {
      float t = bias;
      #pragma unroll
      for (int kk = 0; kk < 4; kk++)
        t += spart[((kk * 5 + j) * 32 + (colh >> 2)) * 4 + (colh & 3)];
      s += fmaxf(t, 0.f);
    }
    v = s * qlin_w[col];
  }
  #pragma unroll
  for (int off = 32; off > 0; off >>= 1) v += __shfl_down(v, off);
  if (tid < 128 && (tid & 63) == 0) s_red[tid >> 6] = v;
  __syncthreads();
  if (tid == 0) ws[OFF_PS + blk] = s_red[0] + s_red[1];
}

// ---------------------------------------------------------------------------
// K3: per-b epilogue (tiny: PS partials + atten maxes). grid = B, 256 thr.
// ---------------------------------------------------------------------------
__global__ __launch_bounds__(256) void k3_final(
    const float* __restrict__ els, const float* __restrict__ elo,
    const float* __restrict__ cate, const float* __restrict__ qlin_b,
    const float* __restrict__ cls_w, const float* __restrict__ cls_b,
    const float* __restrict__ ws, float* __restrict__ out) {
  int b = blockIdx.x;
  int tid = threadIdx.x;
  __shared__ float s_logit[TN], s_p[TN];
  __shared__ float s_at[M * QL];

  const float* attb = ws + OFF_ATT + (size_t)b * M * QL;
  for (int i = tid; i < 800; i += 256)
    *(float4*)&s_at[i * 4] = *(const float4*)&attb[i * 4];

  if (tid < TN) {
    const float* ps = ws + OFF_PS + (size_t)(b * TN + tid) * 4;
    float score = ps[0] + ps[1] + ps[2] + ps[3] + qlin_b[0];
    float lo = elo[b * TN + tid], ls = els[b * TN + tid];
    float c0 = cate[(b * TN + tid) * 2 + 0];
    float c1 = cate[(b * TN + tid) * 2 + 1];
    float logit = lo * cls_w[0] + ls * cls_w[1] + c0 * cls_w[2] +
                  c1 * cls_w[3] + score * cls_w[4] + cls_b[0];
    s_logit[tid] = ((ls + lo) != 0.0f) ? logit : NEGV;
  }
  __syncthreads();

  if (tid == 0) {
    float mx = -INFINITY;
    for (int t = 0; t < TN; t++) mx = fmaxf(mx, s_logit[t]);
    float sm = 0.f;
    for (int t = 0; t < TN; t++) sm += expf(s_logit[t] - mx);
    for (int t = 0; t < TN; t++) s_p[t] = expf(s_logit[t] - mx) / sm;
  }
  if (tid < TN) out[b * TN + tid] = s_logit[tid];
  __syncthreads();

  if (tid < QL) {
    float sacc = 0.f;
    for (int tn2 = 0; tn2 < TN; tn2++) {
      float mxa = -INFINITY;
      #pragma unroll
      for (int al = 0; al < AL; al++) {
        mxa = fmaxf(mxa, s_at[(tn2 * AL + al) * QL + tid]);
      }
      sacc += s_p[tn2] * mxa;
    }
    float mx = sacc;
    #pragma unroll
    for (int off = 16; off > 0; off >>= 1) mx = fmaxf(mx, __shfl_xor(mx, off, 32));
    float ex = expf(sacc - mx);
    float sm = ex;
    #pragma unroll
    for (int off = 16; off > 0; off >>= 1) sm += __shfl_xor(sm, off, 32);
    out[B * TN + b * QL + tid] = ex / sm;
  }
}

// ---------------------------------------------------------------------------
extern "C" void kernel_launch(void* const* d_in, const int* in_sizes, int n_in,
                              void* d_out, int out_size, void* d_ws, size_t ws_size,
                              hipStream_t stream) {
  const int*   q      = (const int*)  d_in[0];
  const int*   alia   = (const int*)  d_in[1];
  const float* els    = (const float*)d_in[2];
  const float* elo    = (const float*)d_in[3];
  const float* cate   = (const float*)d_in[4];
  const float* emb    = (const float*)d_in[5];
  const float* sim_w  = (const float*)d_in[6];
  const float* sim_b  = (const float*)d_in[7];
  const float* enc_w  = (const float*)d_in[8];
  const float* enc_b  = (const float*)d_in[9];
  const float* qlin_w = (const float*)d_in[10];
  const float* qlin_b = (const float*)d_in[11];
  const float* cls_w  = (const float*)d_in[12];
  const float* cls_b  = (const float*)d_in[13];
  float* out = (float*)d_out;
  float* ws  = (float*)d_ws;

  k2_fused<<<320 + 128, 256, 0, stream>>>(q, alia, emb, sim_w, sim_b, enc_w, ws);
  k2b_enc<<<B * TN * 4, 256, 0, stream>>>(enc_w, enc_b, qlin_w, ws);
  k3_final<<<B, 256, 0, stream>>>(els, elo, cate, qlin_b, cls_w, cls_b, ws, out);
}

// Round 10
// 31.496 us; speedup vs baseline: 1.6587x; 1.6587x over previous
//
#include <hip/hip_runtime.h>
#include <math.h>

#define NEGV (-10000000000.0f)

constexpr int B  = 16;
constexpr int QL = 32;
constexpr int TN = 10;
constexpr int AL = 10;
constexpr int E  = 300;
constexpr int H  = 256;
constexpr int M  = TN * AL;     // 100
constexpr int NQ = B * QL;      // 512 q slots
constexpr int NA = B * M;       // 1600 alia slots
constexpr int SQS = 304;        // padded row stride for stored aemb rows

// workspace layout (in floats)
constexpr size_t OFF_AEMB = 0;                                 // NA*SQS
constexpr size_t OFF_ATT  = OFF_AEMB + (size_t)NA * SQS;       // NA*QL
constexpr size_t OFF_P    = OFF_ATT + (size_t)NA * QL;         // NA*QL
constexpr size_t OFF_QW   = OFF_P + (size_t)NA * QL;           // NQ*H
constexpr size_t OFF_PS   = OFF_QW + (size_t)NQ * H;           // 640
// R6: in-graph 64B memset ~19us. R7: device-fence+atomic in 640 blocks ~11us.
// R9: serializing 37 row-norms on one wave ~25us. Lessons encoded below.

// ---------------------------------------------------------------------------
// K2 fused (448 blocks, 256 thr). Gathers + normalizes emb rows itself.
//  role A (blk < 320): per (b,tn,mh): atten (5 m-rows) + softmax -> ATT, P.
//    q-norm + W2 dot FUSED into the dot loop (per-lane, no shfl, no serial
//    pass): acc=sum a3*q, qq=sum q*q, qw=sum w2*q. Wave 3 norms only the 5
//    a-rows concurrently. att = aw1[m] + qw*scQ + acc*scA*scQ + bias.
//  role B (blk >= 320): QW = Qemb_n @ enc_w[:300] (64 rowgroups x 2 halves).
// ---------------------------------------------------------------------------
__global__ __launch_bounds__(256) void k2_fused(
    const int* __restrict__ q, const int* __restrict__ alia,
    const float* __restrict__ emb,
    const float* __restrict__ sim_w, const float* __restrict__ sim_b,
    const float* __restrict__ enc_w, float* __restrict__ ws) {
  __shared__ float smem[13216];      // 52.9 KB -> 3 blocks/CU
  int tid = threadIdx.x;
  int wid = tid >> 6, lane = tid & 63;

  if (blockIdx.x < 320) {
    // ================= role A =================
    int mh = blockIdx.x & 1, btn = blockIdx.x >> 1;
    int b = btn / TN;
    int bm0 = btn * AL + mh * 5;
    float* sq    = smem;                        // [32][308] raw q rows
    float* sa    = smem + 32 * 308;             // [5][304] raw a rows
    float* sa3   = sa + 5 * 304;                // [5][304] raw a * w3
    float* sw2   = sa3 + 5 * 304;               // [304] W2
    float* s_aw1 = sw2 + 304;                   // [8] (W1.a_raw)*scA
    float* s_scA = s_aw1 + 8;                   // [8]

    const float* w3 = sim_w + 2 * E;
    // phase 0: stage raw rows; fold w3 into sa3; stage w2
    for (int i = tid; i < 32 * 75; i += 256) {
      int r = i / 75, e4 = i % 75;
      int idx = q[b * QL + r];
      *(float4*)&sq[r * 308 + e4 * 4] =
          *(const float4*)&emb[(size_t)idx * E + e4 * 4];
    }
    for (int i = tid; i < 5 * 75; i += 256) {
      int j = i / 75, e4 = i % 75;
      int idx = alia[bm0 + j];
      float4 v = *(const float4*)&emb[(size_t)idx * E + e4 * 4];
      float4 wv = *(const float4*)&w3[e4 * 4];
      *(float4*)&sa[j * 304 + e4 * 4] = v;
      float4 t; t.x = v.x*wv.x; t.y = v.y*wv.y; t.z = v.z*wv.z; t.w = v.w*wv.w;
      *(float4*)&sa3[j * 304 + e4 * 4] = t;
    }
    if (tid < 75)
      *(float4*)&sw2[tid * 4] = *(const float4*)&sim_w[E + tid * 4];
    __syncthreads();

    // phase 1: waves 0-2 dot (with fused q-norm + w2 dot); wave 3 norms the
    // 5 a-rows. Balanced: ~75 LDS-iters vs 5 short rows.
    int g = lane & 31, l = lane >> 5;
    int m = wid * 2 + l;                 // 0..5 (5 unused)
    float acc = 0.f, qq = 0.f, qw = 0.f;
    if (wid < 3) {
      const float* qr = &sq[g * 308];
      const float* ar = &sa3[(m % 5) * 304];
      for (int e4 = 0; e4 < 75; ++e4) {
        float4 qv = *(const float4*)&qr[e4 * 4];
        float4 av = *(const float4*)&ar[e4 * 4];
        float4 wv = *(const float4*)&sw2[e4 * 4];
        acc += av.x*qv.x + av.y*qv.y + av.z*qv.z + av.w*qv.w;
        qq  += qv.x*qv.x + qv.y*qv.y + qv.z*qv.z + qv.w*qv.w;
        qw  += wv.x*qv.x + wv.y*qv.y + wv.z*qv.z + wv.w*qv.w;
      }
    } else {
      for (int r = 0; r < 5; ++r) {
        const float* row = &sa[r * 304];
        float ss = 0.f, dw = 0.f;
        for (int e = lane; e < E; e += 64) {
          float v = row[e];
          ss += v * v;
          dw += v * sim_w[e];
        }
        #pragma unroll
        for (int off = 32; off > 0; off >>= 1) {
          ss += __shfl_xor(ss, off);
          dw += __shfl_xor(dw, off);
        }
        if (lane == 0) {
          int idx = alia[bm0 + r];
          float sc = (idx == 0) ? 0.f : (1.f / fmaxf(sqrtf(ss), 1e-12f));
          s_scA[r] = sc;
          s_aw1[r] = dw * sc;
        }
      }
    }
    __syncthreads();

    // phase 2: write normalized aemb rows; finalize att + softmax
    for (int i = tid; i < 5 * 75; i += 256) {
      int j = i / 75, e4 = i % 75;
      float sc = s_scA[j];
      float4 v = *(const float4*)&sa[j * 304 + e4 * 4];
      float4 vn; vn.x = v.x*sc; vn.y = v.y*sc; vn.z = v.z*sc; vn.w = v.w*sc;
      *(float4*)&ws[OFF_AEMB + (size_t)(bm0 + j) * SQS + e4 * 4] = vn;
    }
    if (wid < 3 && m < 5) {
      int bm = bm0 + m;
      int qidx = q[b * QL + g];
      float scQ = (qidx == 0) ? 0.f : (1.f / fmaxf(sqrtf(qq), 1e-12f));
      float att = s_aw1[m] + qw * scQ + acc * s_scA[m] * scQ + sim_b[0];
      if (!(alia[bm] != 0 && qidx != 0)) att = NEGV;
      ws[OFF_ATT + (size_t)bm * QL + g] = att;
      float mx = att;
      #pragma unroll
      for (int off = 1; off < 32; off <<= 1) mx = fmaxf(mx, __shfl_xor(mx, off));
      float ex = expf(att - mx);
      float sm = ex;
      #pragma unroll
      for (int off = 1; off < 32; off <<= 1) sm += __shfl_xor(sm, off);
      ws[OFF_P + (size_t)bm * QL + g] = ex / sm;
    }
  } else {
    // ================= role B: QW GEMM (512 x 300 @ 300 x 256) ============
    int rg = blockIdx.x - 320;
    int nh = rg & 1, rgi = rg >> 1;     // 64 rowgroups of 8 q-slots
    int slot0 = rgi * 8;
    float* sQ = smem;                   // [8][304] raw q rows
    float* spart = smem + 8 * 304;      // [kq2][j][c][4] = 4096
    float* s_scB = spart + 4096;        // [8]

    for (int i = tid; i < 8 * 75; i += 256) {
      int r = i / 75, e4 = i % 75;
      int idx = q[slot0 + r];
      *(float4*)&sQ[r * 304 + e4 * 4] =
          *(const float4*)&emb[(size_t)idx * E + e4 * 4];
    }
    __syncthreads();
    for (int r = wid; r < 8; r += 4) {
      const float* row = &sQ[r * 304];
      float ss = 0.f;
      for (int e = lane; e < E; e += 64) { float v = row[e]; ss += v * v; }
      #pragma unroll
      for (int off = 32; off > 0; off >>= 1) ss += __shfl_xor(ss, off);
      if (lane == 0) {
        int idx = q[slot0 + r];
        s_scB[r] = (idx == 0) ? 0.f : (1.f / fmaxf(sqrtf(ss), 1e-12f));
      }
    }
    __syncthreads();

    int c = tid & 31, kq = tid >> 5;    // thread handles cols c*4..c*4+3
    int ks = kq * 40;
    int nch = (kq == 7) ? 5 : 10;       // 7*40 + 20 = 300
    float acc[8][4] = {};
    for (int ch = 0; ch < nch; ++ch) {
      int k = ks + ch * 4;
      float4 a[8];
      #pragma unroll
      for (int j = 0; j < 8; j++) a[j] = *(const float4*)&sQ[j * 304 + k];
      const float* wp = enc_w + (size_t)k * H + nh * 128 + c * 4;
      #pragma unroll
      for (int e = 0; e < 4; e++) {
        float4 wv = *(const float4*)&wp[e * H];
        #pragma unroll
        for (int j = 0; j < 8; j++) {
          float av = (e == 0) ? a[j].x : (e == 1) ? a[j].y
                   : (e == 2) ? a[j].z : a[j].w;
          acc[j][0] += av * wv.x; acc[j][1] += av * wv.y;
          acc[j][2] += av * wv.z; acc[j][3] += av * wv.w;
        }
      }
    }
    // kq-pair pre-reduce across the wave halves (kq, kq^1)
    #pragma unroll
    for (int j = 0; j < 8; j++)
      #pragma unroll
      for (int nc = 0; nc < 4; nc++) acc[j][nc] += __shfl_xor(acc[j][nc], 32);
    if ((kq & 1) == 0) {
      int kq2 = kq >> 1;
      #pragma unroll
      for (int j = 0; j < 8; j++) {
        float4 t; t.x = acc[j][0]; t.y = acc[j][1]; t.z = acc[j][2]; t.w = acc[j][3];
        *(float4*)&spart[((kq2 * 8 + j) * 32 + c) * 4] = t;
      }
    }
    __syncthreads();
    #pragma unroll
    for (int t = 0; t < 4; t++) {
      int o = tid + t * 256;
      int j = o >> 7, colh = o & 127;
      float s = 0.f;
      #pragma unroll
      for (int kk = 0; kk < 4; kk++)
        s += spart[((kk * 8 + j) * 32 + (colh >> 2)) * 4 + (colh & 3)];
      ws[OFF_QW + (size_t)(slot0 + j) * H + nh * 128 + colh] = s * s_scB[j];
    }
  }
}

// ---------------------------------------------------------------------------
// K2b: enc = relu(P@QW + aemb_n@W2enc + bias), summed over 5-row half, dotted
// with qlin_w -> PS[blk]. No atomics/fences. 17 KB LDS.
// grid = 640 blocks (btn, jh, nh), 256 threads = 32c x 8kq.
// ---------------------------------------------------------------------------
__global__ __launch_bounds__(256) void k2b_enc(
    const float* __restrict__ enc_w, const float* __restrict__ enc_b,
    const float* __restrict__ qlin_w, float* __restrict__ ws) {
  int blk = blockIdx.x;
  int nh = blk & 1, jh = (blk >> 1) & 1, btn = blk >> 2;
  int b = btn / TN;
  int tid = threadIdx.x;
  int c = tid & 31, kq = tid >> 5;    // thread handles cols c*4..c*4+3
  int bm0 = btn * AL + jh * 5;

  __shared__ float sA[5 * 304];
  __shared__ float sP[5 * 32];
  __shared__ float spart[4 * 5 * 32 * 4];   // kq-pair-reduced partials
  __shared__ float s_red[2];

  const float* ga = ws + OFF_AEMB + (size_t)bm0 * SQS;
  for (int i = tid; i < 5 * 75; i += 256) {
    int j = i / 75, e4 = i % 75;
    *(float4*)&sA[j * 304 + e4 * 4] = *(const float4*)&ga[j * SQS + e4 * 4];
  }
  if (tid < 160) sP[tid] = ws[OFF_P + (size_t)bm0 * QL + tid];
  __syncthreads();

  float acc[5][4] = {};

  // P @ QW part: this kq handles pk = kq*4 .. kq*4+3
  {
    float4 pv[5];
    #pragma unroll
    for (int j = 0; j < 5; j++) pv[j] = *(const float4*)&sP[j * 32 + kq * 4];
    const float* qwb = ws + OFF_QW + (size_t)(b * QL + kq * 4) * H + nh * 128 + c * 4;
    #pragma unroll
    for (int pp = 0; pp < 4; pp++) {
      float4 wv = *(const float4*)&qwb[pp * H];
      #pragma unroll
      for (int j = 0; j < 5; j++) {
        float p = (pp == 0) ? pv[j].x : (pp == 1) ? pv[j].y
                : (pp == 2) ? pv[j].z : pv[j].w;
        acc[j][0] += p * wv.x; acc[j][1] += p * wv.y;
        acc[j][2] += p * wv.z; acc[j][3] += p * wv.w;
      }
    }
  }

  // aemb_n @ W2enc part
  int ks = kq * 40;
  int nch = (kq == 7) ? 5 : 10;         // 7*40 + 20 = 300
  for (int ch = 0; ch < nch; ++ch) {
    int k = ks + ch * 4;
    float4 a[5];
    #pragma unroll
    for (int j = 0; j < 5; j++) a[j] = *(const float4*)&sA[j * 304 + k];
    const float* wp = enc_w + (size_t)(E + k) * H + nh * 128 + c * 4;
    #pragma unroll
    for (int e = 0; e < 4; e++) {
      float4 wv = *(const float4*)&wp[e * H];
      #pragma unroll
      for (int j = 0; j < 5; j++) {
        float av = (e == 0) ? a[j].x : (e == 1) ? a[j].y
                 : (e == 2) ? a[j].z : a[j].w;
        acc[j][0] += av * wv.x; acc[j][1] += av * wv.y;
        acc[j][2] += av * wv.z; acc[j][3] += av * wv.w;
      }
    }
  }

  // kq-pair pre-reduce across wave halves, then 4-deep LDS partials
  #pragma unroll
  for (int j = 0; j < 5; j++)
    #pragma unroll
    for (int nc = 0; nc < 4; nc++) acc[j][nc] += __shfl_xor(acc[j][nc], 32);
  if ((kq & 1) == 0) {
    int kq2 = kq >> 1;
    #pragma unroll
    for (int j = 0; j < 5; j++) {
      float4 t; t.x = acc[j][0]; t.y = acc[j][1]; t.z = acc[j][2]; t.w = acc[j][3];
      *(float4*)&spart[((kq2 * 5 + j) * 32 + c) * 4] = t;
    }
  }
  __syncthreads();

  float v = 0.f;
  if (tid < 128) {
    int colh = tid, col = nh * 128 + colh;
    float bias = enc_b[col];
    float s = 0.f;
    #pragma unroll
    for (int j = 0; j < 5; j++) {
      float t = bias;
      #pragma unroll
      for (int kk = 0; kk < 4; kk++)
        t += spart[((kk * 5 + j) * 32 + (colh >> 2)) * 4 + (colh & 3)];
      s += fmaxf(t, 0.f);
    }
    v = s * qlin_w[col];
  }
  #pragma unroll
  for (int off = 32; off > 0; off >>= 1) v += __shfl_down(v, off);
  if (tid < 128 && (tid & 63) == 0) s_red[tid >> 6] = v;
  __syncthreads();
  if (tid == 0) ws[OFF_PS + blk] = s_red[0] + s_red[1];
}

// ---------------------------------------------------------------------------
// K3: per-b epilogue (tiny: PS partials + atten maxes). grid = B, 256 thr.
// ---------------------------------------------------------------------------
__global__ __launch_bounds__(256) void k3_final(
    const float* __restrict__ els, const float* __restrict__ elo,
    const float* __restrict__ cate, const float* __restrict__ qlin_b,
    const float* __restrict__ cls_w, const float* __restrict__ cls_b,
    const float* __restrict__ ws, float* __restrict__ out) {
  int b = blockIdx.x;
  int tid = threadIdx.x;
  __shared__ float s_logit[TN], s_p[TN];
  __shared__ float s_at[M * QL];

  const float* attb = ws + OFF_ATT + (size_t)b * M * QL;
  for (int i = tid; i < 800; i += 256)
    *(float4*)&s_at[i * 4] = *(const float4*)&attb[i * 4];

  if (tid < TN) {
    const float* ps = ws + OFF_PS + (size_t)(b * TN + tid) * 4;
    float score = ps[0] + ps[1] + ps[2] + ps[3] + qlin_b[0];
    float lo = elo[b * TN + tid], ls = els[b * TN + tid];
    float c0 = cate[(b * TN + tid) * 2 + 0];
    float c1 = cate[(b * TN + tid) * 2 + 1];
    float logit = lo * cls_w[0] + ls * cls_w[1] + c0 * cls_w[2] +
                  c1 * cls_w[3] + score * cls_w[4] + cls_b[0];
    s_logit[tid] = ((ls + lo) != 0.0f) ? logit : NEGV;
  }
  __syncthreads();

  if (tid == 0) {
    float mx = -INFINITY;
    for (int t = 0; t < TN; t++) mx = fmaxf(mx, s_logit[t]);
    float sm = 0.f;
    for (int t = 0; t < TN; t++) sm += expf(s_logit[t] - mx);
    for (int t = 0; t < TN; t++) s_p[t] = expf(s_logit[t] - mx) / sm;
  }
  if (tid < TN) out[b * TN + tid] = s_logit[tid];
  __syncthreads();

  if (tid < QL) {
    float sacc = 0.f;
    for (int tn2 = 0; tn2 < TN; tn2++) {
      float mxa = -INFINITY;
      #pragma unroll
      for (int al = 0; al < AL; al++) {
        mxa = fmaxf(mxa, s_at[(tn2 * AL + al) * QL + tid]);
      }
      sacc += s_p[tn2] * mxa;
    }
    float mx = sacc;
    #pragma unroll
    for (int off = 16; off > 0; off >>= 1) mx = fmaxf(mx, __shfl_xor(mx, off, 32));
    float ex = expf(sacc - mx);
    float sm = ex;
    #pragma unroll
    for (int off = 16; off > 0; off >>= 1) sm += __shfl_xor(sm, off, 32);
    out[B * TN + b * QL + tid] = ex / sm;
  }
}

// ---------------------------------------------------------------------------
extern "C" void kernel_launch(void* const* d_in, const int* in_sizes, int n_in,
                              void* d_out, int out_size, void* d_ws, size_t ws_size,
                              hipStream_t stream) {
  const int*   q      = (const int*)  d_in[0];
  const int*   alia   = (const int*)  d_in[1];
  const float* els    = (const float*)d_in[2];
  const float* elo    = (const float*)d_in[3];
  const float* cate   = (const float*)d_in[4];
  const float* emb    = (const float*)d_in[5];
  const float* sim_w  = (const float*)d_in[6];
  const float* sim_b  = (const float*)d_in[7];
  const float* enc_w  = (const float*)d_in[8];
  const float* enc_b  = (const float*)d_in[9];
  const float* qlin_w = (const float*)d_in[10];
  const float* qlin_b = (const float*)d_in[11];
  const float* cls_w  = (const float*)d_in[12];
  const float* cls_b  = (const float*)d_in[13];
  float* out = (float*)d_out;
  float* ws  = (float*)d_ws;

  k2_fused<<<320 + 128, 256, 0, stream>>>(q, alia, emb, sim_w, sim_b, enc_w, ws);
  k2b_enc<<<B * TN * 4, 256, 0, stream>>>(enc_w, enc_b, qlin_w, ws);
  k3_final<<<B, 256, 0, stream>>>(els, elo, cate, qlin_b, cls_w, cls_b, ws, out);
}

// Round 11
// 31.055 us; speedup vs baseline: 1.6823x; 1.0142x over previous
//
#include <hip/hip_runtime.h>
#include <math.h>

#define NEGV (-10000000000.0f)

constexpr int B  = 16;
constexpr int QL = 32;
constexpr int TN = 10;
constexpr int AL = 10;
constexpr int E  = 300;
constexpr int H  = 256;
constexpr int M  = TN * AL;     // 100
constexpr int NQ = B * QL;      // 512 q slots
constexpr int NA = B * M;       // 1600 alia slots
constexpr int SQS = 304;        // padded row stride for stored aemb rows

// workspace layout (in floats)
constexpr size_t OFF_AEMB = 0;                                 // NA*SQS
constexpr size_t OFF_ATT  = OFF_AEMB + (size_t)NA * SQS;       // NA*QL
constexpr size_t OFF_P    = OFF_ATT + (size_t)NA * QL;         // NA*QL
constexpr size_t OFF_QW   = OFF_P + (size_t)NA * QL;           // NQ*H
constexpr size_t OFF_PS   = OFF_QW + (size_t)NQ * H;           // 320
// R6: in-graph 64B memset ~19us. R7: device-fence+atomic in 640 blocks ~11us.
// R9: serializing 37 row-norms on one wave ~25us. Lessons encoded below.

// ---------------------------------------------------------------------------
// K2 fused (448 blocks, 256 thr). Gathers + normalizes emb rows itself.
//  role A (blk < 320): per (b,tn,mh): atten (5 m-rows) + softmax -> ATT, P.
//    q-norm + W2 dot fused into the dot loop (per-lane, no shfl). Wave 3
//    norms only the 5 a-rows. att = aw1[m] + qw*scQ + acc*scA*scQ + bias.
//  role B (blk >= 320): QW = Qemb_n @ enc_w[:300] (64 rowgroups x 2 halves).
// ---------------------------------------------------------------------------
__global__ __launch_bounds__(256) void k2_fused(
    const int* __restrict__ q, const int* __restrict__ alia,
    const float* __restrict__ emb,
    const float* __restrict__ sim_w, const float* __restrict__ sim_b,
    const float* __restrict__ enc_w, float* __restrict__ ws) {
  __shared__ float smem[13216];      // 52.9 KB -> 3 blocks/CU
  int tid = threadIdx.x;
  int wid = tid >> 6, lane = tid & 63;

  if (blockIdx.x < 320) {
    // ================= role A =================
    int mh = blockIdx.x & 1, btn = blockIdx.x >> 1;
    int b = btn / TN;
    int bm0 = btn * AL + mh * 5;
    float* sq    = smem;                        // [32][308] raw q rows
    float* sa    = smem + 32 * 308;             // [5][304] raw a rows
    float* sa3   = sa + 5 * 304;                // [5][304] raw a * w3
    float* sw2   = sa3 + 5 * 304;               // [304] W2
    float* s_aw1 = sw2 + 304;                   // [8] (W1.a_raw)*scA
    float* s_scA = s_aw1 + 8;                   // [8]

    const float* w3 = sim_w + 2 * E;
    // phase 0: stage raw rows; fold w3 into sa3; stage w2
    for (int i = tid; i < 32 * 75; i += 256) {
      int r = i / 75, e4 = i % 75;
      int idx = q[b * QL + r];
      *(float4*)&sq[r * 308 + e4 * 4] =
          *(const float4*)&emb[(size_t)idx * E + e4 * 4];
    }
    for (int i = tid; i < 5 * 75; i += 256) {
      int j = i / 75, e4 = i % 75;
      int idx = alia[bm0 + j];
      float4 v = *(const float4*)&emb[(size_t)idx * E + e4 * 4];
      float4 wv = *(const float4*)&w3[e4 * 4];
      *(float4*)&sa[j * 304 + e4 * 4] = v;
      float4 t; t.x = v.x*wv.x; t.y = v.y*wv.y; t.z = v.z*wv.z; t.w = v.w*wv.w;
      *(float4*)&sa3[j * 304 + e4 * 4] = t;
    }
    if (tid < 75)
      *(float4*)&sw2[tid * 4] = *(const float4*)&sim_w[E + tid * 4];
    __syncthreads();

    // phase 1: waves 0-2 dot (with fused q-norm + w2 dot); wave 3 norms the
    // 5 a-rows concurrently.
    int g = lane & 31, l = lane >> 5;
    int m = wid * 2 + l;                 // 0..5 (5 unused)
    float acc = 0.f, qq = 0.f, qw = 0.f;
    if (wid < 3) {
      const float* qr = &sq[g * 308];
      const float* ar = &sa3[(m % 5) * 304];
      for (int e4 = 0; e4 < 75; ++e4) {
        float4 qv = *(const float4*)&qr[e4 * 4];
        float4 av = *(const float4*)&ar[e4 * 4];
        float4 wv = *(const float4*)&sw2[e4 * 4];
        acc += av.x*qv.x + av.y*qv.y + av.z*qv.z + av.w*qv.w;
        qq  += qv.x*qv.x + qv.y*qv.y + qv.z*qv.z + qv.w*qv.w;
        qw  += wv.x*qv.x + wv.y*qv.y + wv.z*qv.z + wv.w*qv.w;
      }
    } else {
      for (int r = 0; r < 5; ++r) {
        const float* row = &sa[r * 304];
        float ss = 0.f, dw = 0.f;
        for (int e = lane; e < E; e += 64) {
          float v = row[e];
          ss += v * v;
          dw += v * sim_w[e];
        }
        #pragma unroll
        for (int off = 32; off > 0; off >>= 1) {
          ss += __shfl_xor(ss, off);
          dw += __shfl_xor(dw, off);
        }
        if (lane == 0) {
          int idx = alia[bm0 + r];
          float sc = (idx == 0) ? 0.f : (1.f / fmaxf(sqrtf(ss), 1e-12f));
          s_scA[r] = sc;
          s_aw1[r] = dw * sc;
        }
      }
    }
    __syncthreads();

    // phase 2: write normalized aemb rows; finalize att + softmax
    for (int i = tid; i < 5 * 75; i += 256) {
      int j = i / 75, e4 = i % 75;
      float sc = s_scA[j];
      float4 v = *(const float4*)&sa[j * 304 + e4 * 4];
      float4 vn; vn.x = v.x*sc; vn.y = v.y*sc; vn.z = v.z*sc; vn.w = v.w*sc;
      *(float4*)&ws[OFF_AEMB + (size_t)(bm0 + j) * SQS + e4 * 4] = vn;
    }
    if (wid < 3 && m < 5) {
      int bm = bm0 + m;
      int qidx = q[b * QL + g];
      float scQ = (qidx == 0) ? 0.f : (1.f / fmaxf(sqrtf(qq), 1e-12f));
      float att = s_aw1[m] + qw * scQ + acc * s_scA[m] * scQ + sim_b[0];
      if (!(alia[bm] != 0 && qidx != 0)) att = NEGV;
      ws[OFF_ATT + (size_t)bm * QL + g] = att;
      float mx = att;
      #pragma unroll
      for (int off = 1; off < 32; off <<= 1) mx = fmaxf(mx, __shfl_xor(mx, off));
      float ex = expf(att - mx);
      float sm = ex;
      #pragma unroll
      for (int off = 1; off < 32; off <<= 1) sm += __shfl_xor(sm, off);
      ws[OFF_P + (size_t)bm * QL + g] = ex / sm;
    }
  } else {
    // ================= role B: QW GEMM (512 x 300 @ 300 x 256) ============
    int rg = blockIdx.x - 320;
    int nh = rg & 1, rgi = rg >> 1;     // 64 rowgroups of 8 q-slots
    int slot0 = rgi * 8;
    float* sQ = smem;                   // [8][304] raw q rows
    float* spart = smem + 8 * 304;      // [kq2][j][c][4] = 4096
    float* s_scB = spart + 4096;        // [8]

    for (int i = tid; i < 8 * 75; i += 256) {
      int r = i / 75, e4 = i % 75;
      int idx = q[slot0 + r];
      *(float4*)&sQ[r * 304 + e4 * 4] =
          *(const float4*)&emb[(size_t)idx * E + e4 * 4];
    }
    __syncthreads();
    for (int r = wid; r < 8; r += 4) {
      const float* row = &sQ[r * 304];
      float ss = 0.f;
      for (int e = lane; e < E; e += 64) { float v = row[e]; ss += v * v; }
      #pragma unroll
      for (int off = 32; off > 0; off >>= 1) ss += __shfl_xor(ss, off);
      if (lane == 0) {
        int idx = q[slot0 + r];
        s_scB[r] = (idx == 0) ? 0.f : (1.f / fmaxf(sqrtf(ss), 1e-12f));
      }
    }
    __syncthreads();

    int c = tid & 31, kq = tid >> 5;    // thread handles cols c*4..c*4+3
    int ks = kq * 40;
    int nch = (kq == 7) ? 5 : 10;       // 7*40 + 20 = 300
    float acc[8][4] = {};
    for (int ch = 0; ch < nch; ++ch) {
      int k = ks + ch * 4;
      float4 a[8];
      #pragma unroll
      for (int j = 0; j < 8; j++) a[j] = *(const float4*)&sQ[j * 304 + k];
      const float* wp = enc_w + (size_t)k * H + nh * 128 + c * 4;
      #pragma unroll
      for (int e = 0; e < 4; e++) {
        float4 wv = *(const float4*)&wp[e * H];
        #pragma unroll
        for (int j = 0; j < 8; j++) {
          float av = (e == 0) ? a[j].x : (e == 1) ? a[j].y
                   : (e == 2) ? a[j].z : a[j].w;
          acc[j][0] += av * wv.x; acc[j][1] += av * wv.y;
          acc[j][2] += av * wv.z; acc[j][3] += av * wv.w;
        }
      }
    }
    // kq-pair pre-reduce across the wave halves (kq, kq^1)
    #pragma unroll
    for (int j = 0; j < 8; j++)
      #pragma unroll
      for (int nc = 0; nc < 4; nc++) acc[j][nc] += __shfl_xor(acc[j][nc], 32);
    if ((kq & 1) == 0) {
      int kq2 = kq >> 1;
      #pragma unroll
      for (int j = 0; j < 8; j++) {
        float4 t; t.x = acc[j][0]; t.y = acc[j][1]; t.z = acc[j][2]; t.w = acc[j][3];
        *(float4*)&spart[((kq2 * 8 + j) * 32 + c) * 4] = t;
      }
    }
    __syncthreads();
    #pragma unroll
    for (int t = 0; t < 4; t++) {
      int o = tid + t * 256;
      int j = o >> 7, colh = o & 127;
      float s = 0.f;
      #pragma unroll
      for (int kk = 0; kk < 4; kk++)
        s += spart[((kk * 8 + j) * 32 + (colh >> 2)) * 4 + (colh & 3)];
      ws[OFF_QW + (size_t)(slot0 + j) * H + nh * 128 + colh] = s * s_scB[j];
    }
  }
}

// ---------------------------------------------------------------------------
// K2b: enc = relu(P@QW + aemb_n@W2enc + bias), summed over ALL 10 rows of the
// (b,tn), dotted with qlin_w -> PS[btn*2+nh]. jh-merged: each enc_w fetch now
// feeds 10 rows (was 5) -> half the weight traffic of R10.
// grid = 320 blocks (btn, nh), 256 threads = 32c x 8kq.
// ---------------------------------------------------------------------------
__global__ __launch_bounds__(256) void k2b_enc(
    const float* __restrict__ enc_w, const float* __restrict__ enc_b,
    const float* __restrict__ qlin_w, float* __restrict__ ws) {
  int blk = blockIdx.x;
  int nh = blk & 1, btn = blk >> 1;
  int b = btn / TN;
  int tid = threadIdx.x;
  int c = tid & 31, kq = tid >> 5;    // thread handles cols c*4..c*4+3
  int bm0 = btn * AL;

  __shared__ float sA[10 * 304];             // 12.2 KB
  __shared__ float sP[10 * 32];
  __shared__ float spart[4 * 10 * 32 * 4];   // 20.5 KB
  __shared__ float s_red[2];

  const float* ga = ws + OFF_AEMB + (size_t)bm0 * SQS;
  for (int i = tid; i < 10 * 75; i += 256) {
    int j = i / 75, e4 = i % 75;
    *(float4*)&sA[j * 304 + e4 * 4] = *(const float4*)&ga[j * SQS + e4 * 4];
  }
  for (int i = tid; i < 10 * 32; i += 256)
    sP[i] = ws[OFF_P + (size_t)bm0 * QL + i];
  __syncthreads();

  float acc[10][4] = {};

  // P @ QW part: this kq handles pk = kq*4 .. kq*4+3
  {
    const float* qwb = ws + OFF_QW + (size_t)(b * QL + kq * 4) * H + nh * 128 + c * 4;
    #pragma unroll
    for (int pp = 0; pp < 4; pp++) {
      float4 wv = *(const float4*)&qwb[pp * H];
      #pragma unroll
      for (int j = 0; j < 10; j++) {
        float p = sP[j * 32 + kq * 4 + pp];   // half-wave-uniform broadcast
        acc[j][0] += p * wv.x; acc[j][1] += p * wv.y;
        acc[j][2] += p * wv.z; acc[j][3] += p * wv.w;
      }
    }
  }

  // aemb_n @ W2enc part
  int ks = kq * 40;
  int nch = (kq == 7) ? 5 : 10;         // 7*40 + 20 = 300
  for (int ch = 0; ch < nch; ++ch) {
    int k = ks + ch * 4;
    const float* wp = enc_w + (size_t)(E + k) * H + nh * 128 + c * 4;
    #pragma unroll
    for (int e = 0; e < 4; e++) {
      float4 wv = *(const float4*)&wp[e * H];
      #pragma unroll
      for (int j = 0; j < 10; j++) {
        float av = sA[j * 304 + k + e];     // half-wave-uniform broadcast
        acc[j][0] += av * wv.x; acc[j][1] += av * wv.y;
        acc[j][2] += av * wv.z; acc[j][3] += av * wv.w;
      }
    }
  }

  // kq-pair pre-reduce across wave halves, then 4-deep LDS partials
  #pragma unroll
  for (int j = 0; j < 10; j++)
    #pragma unroll
    for (int nc = 0; nc < 4; nc++) acc[j][nc] += __shfl_xor(acc[j][nc], 32);
  if ((kq & 1) == 0) {
    int kq2 = kq >> 1;
    #pragma unroll
    for (int j = 0; j < 10; j++) {
      float4 t; t.x = acc[j][0]; t.y = acc[j][1]; t.z = acc[j][2]; t.w = acc[j][3];
      *(float4*)&spart[((kq2 * 10 + j) * 32 + c) * 4] = t;
    }
  }
  __syncthreads();

  float v = 0.f;
  if (tid < 128) {
    int colh = tid, col = nh * 128 + colh;
    float bias = enc_b[col];
    float s = 0.f;
    #pragma unroll
    for (int j = 0; j < 10; j++) {
      float t = bias;
      #pragma unroll
      for (int kk = 0; kk < 4; kk++)
        t += spart[((kk * 10 + j) * 32 + (colh >> 2)) * 4 + (colh & 3)];
      s += fmaxf(t, 0.f);
    }
    v = s * qlin_w[col];
  }
  #pragma unroll
  for (int off = 32; off > 0; off >>= 1) v += __shfl_down(v, off);
  if (tid < 128 && (tid & 63) == 0) s_red[tid >> 6] = v;
  __syncthreads();
  if (tid == 0) ws[OFF_PS + blk] = s_red[0] + s_red[1];
}

// ---------------------------------------------------------------------------
// K3: per-b epilogue (tiny: PS partials + atten maxes). grid = B, 256 thr.
// ---------------------------------------------------------------------------
__global__ __launch_bounds__(256) void k3_final(
    const float* __restrict__ els, const float* __restrict__ elo,
    const float* __restrict__ cate, const float* __restrict__ qlin_b,
    const float* __restrict__ cls_w, const float* __restrict__ cls_b,
    const float* __restrict__ ws, float* __restrict__ out) {
  int b = blockIdx.x;
  int tid = threadIdx.x;
  __shared__ float s_logit[TN], s_p[TN];
  __shared__ float s_at[M * QL];

  const float* attb = ws + OFF_ATT + (size_t)b * M * QL;
  for (int i = tid; i < 800; i += 256)
    *(float4*)&s_at[i * 4] = *(const float4*)&attb[i * 4];

  if (tid < TN) {
    const float* ps = ws + OFF_PS + (size_t)(b * TN + tid) * 2;
    float score = ps[0] + ps[1] + qlin_b[0];
    float lo = elo[b * TN + tid], ls = els[b * TN + tid];
    float c0 = cate[(b * TN + tid) * 2 + 0];
    float c1 = cate[(b * TN + tid) * 2 + 1];
    float logit = lo * cls_w[0] + ls * cls_w[1] + c0 * cls_w[2] +
                  c1 * cls_w[3] + score * cls_w[4] + cls_b[0];
    s_logit[tid] = ((ls + lo) != 0.0f) ? logit : NEGV;
  }
  __syncthreads();

  if (tid == 0) {
    float mx = -INFINITY;
    for (int t = 0; t < TN; t++) mx = fmaxf(mx, s_logit[t]);
    float sm = 0.f;
    for (int t = 0; t < TN; t++) sm += expf(s_logit[t] - mx);
    for (int t = 0; t < TN; t++) s_p[t] = expf(s_logit[t] - mx) / sm;
  }
  if (tid < TN) out[b * TN + tid] = s_logit[tid];
  __syncthreads();

  if (tid < QL) {
    float sacc = 0.f;
    for (int tn2 = 0; tn2 < TN; tn2++) {
      float mxa = -INFINITY;
      #pragma unroll
      for (int al = 0; al < AL; al++) {
        mxa = fmaxf(mxa, s_at[(tn2 * AL + al) * QL + tid]);
      }
      sacc += s_p[tn2] * mxa;
    }
    float mx = sacc;
    #pragma unroll
    for (int off = 16; off > 0; off >>= 1) mx = fmaxf(mx, __shfl_xor(mx, off, 32));
    float ex = expf(sacc - mx);
    float sm = ex;
    #pragma unroll
    for (int off = 16; off > 0; off >>= 1) sm += __shfl_xor(sm, off, 32);
    out[B * TN + b * QL + tid] = ex / sm;
  }
}

// ---------------------------------------------------------------------------
extern "C" void kernel_launch(void* const* d_in, const int* in_sizes, int n_in,
                              void* d_out, int out_size, void* d_ws, size_t ws_size,
                              hipStream_t stream) {
  const int*   q      = (const int*)  d_in[0];
  const int*   alia   = (const int*)  d_in[1];
  const float* els    = (const float*)d_in[2];
  const float* elo    = (const float*)d_in[3];
  const float* cate   = (const float*)d_in[4];
  const float* emb    = (const float*)d_in[5];
  const float* sim_w  = (const float*)d_in[6];
  const float* sim_b  = (const float*)d_in[7];
  const float* enc_w  = (const float*)d_in[8];
  const float* enc_b  = (const float*)d_in[9];
  const float* qlin_w = (const float*)d_in[10];
  const float* qlin_b = (const float*)d_in[11];
  const float* cls_w  = (const float*)d_in[12];
  const float* cls_b  = (const float*)d_in[13];
  float* out = (float*)d_out;
  float* ws  = (float*)d_ws;

  k2_fused<<<320 + 128, 256, 0, stream>>>(q, alia, emb, sim_w, sim_b, enc_w, ws);
  k2b_enc<<<B * TN * 2, 256, 0, stream>>>(enc_w, enc_b, qlin_w, ws);
  k3_final<<<B, 256, 0, stream>>>(els, elo, cate, qlin_b, cls_w, cls_b, ws, out);
}